// Round 4
// baseline (488.186 us; speedup 1.0000x reference)
//
#include <hip/hip_runtime.h>
#include <hip/hip_fp16.h>
#include <math.h>

// ---------------------------------------------------------------------------
// ADCGNN amazon: N=50000, E=1.6M, IN=128, H=64, C=2, K=3
//
// R5: fp16 gather rows (FETCH halved; time flat) -> gather not byte-bound.
// R6: 8-lane/row retile (instrs halved; +9%, occ down) -> not instr-bound.
// R7: wave-private LDS + readlane GEMVs: 142->120us, VALUBusy 74% -> tail is
//     now VALU-bound on the per-node wave-GEMVs (weights re-streamed/node).
// R8 (this round): algebraic expansion. All tail GEMVs are linear in
//     h/u1/u2/res -> precompute P_x = x@Wf1top, R_x = x@W3 etc. in
//     thread-per-node kernels (weights amortized across 64 nodes/wave via
//     scalar loads). Old tail becomes pure gather (spmm2_k) + tiny final_k.
//
// Pipeline:
//   build: bucket_count -> bucket_scan -> bucket_scatter -> csr_build
//   dense1:    h1 = relu(X@W1+b1)
//   dense2res: h, hs=f16(h*dinv), th=h.Wattn, res, and P_h,QhB,R_h,R_resb
//   spmm1:     u1 = dinv*(A^T hs), u1s = f16(u1*dinv), ta = u1.Wattn
//   dense_u1:  P_u1 = u1@Wf1top, R_u1 = u1@W3
//   spmm2:     u2 = dinv*(A^T u1s) -> u2s f16, tb = u2.Wattn
//   final:     thread/node: P_u2,R_u2 GEMVs + softmax + fusion + logits
// ---------------------------------------------------------------------------

#define BSHIFT 7
#define BNODES 128
#define BMAX   512
#define EPT    32
#define CHUNK  (256 * EPT)
#define CAP    8192

__device__ __forceinline__ void fma4(float4& acc, float s, const float4 w) {
    acc.x += s * w.x; acc.y += s * w.y; acc.z += s * w.z; acc.w += s * w.w;
}

// pack 4 floats -> 4 halves carried in a float2
__device__ __forceinline__ float2 pack_half4(float x, float y, float z, float w) {
    union { __half2 h[2]; float2 f; } u;
    u.h[0] = __floats2half2_rn(x, y);
    u.h[1] = __floats2half2_rn(z, w);
    return u.f;
}

// unpack 4 halves (in a float2) and accumulate into a float4 (fp32)
__device__ __forceinline__ void acch4(float4& a, float2 p) {
    union { float2 f; __half2 h[2]; } u; u.f = p;
    float2 lo = __half22float2(u.h[0]);
    float2 hi = __half22float2(u.h[1]);
    a.x += lo.x; a.y += lo.y; a.z += hi.x; a.w += hi.y;
}

// ----------------------------- graph build ---------------------------------

__global__ __launch_bounds__(256) void bucket_count_k(const int* __restrict__ dst,
                                                      int* __restrict__ bucketCount,
                                                      int E, int B) {
    __shared__ int cnt[BMAX];
    for (int i = threadIdx.x; i < B; i += 256) cnt[i] = 0;
    __syncthreads();
    int base = blockIdx.x * CHUNK;
    #pragma unroll
    for (int t = 0; t < EPT; t++) {
        int e = base + t * 256 + threadIdx.x;
        if (e < E) atomicAdd(&cnt[dst[e] >> BSHIFT], 1);
    }
    __syncthreads();
    for (int i = threadIdx.x; i < B; i += 256)
        if (cnt[i] > 0) atomicAdd(&bucketCount[i], cnt[i]);
}

__global__ __launch_bounds__(64) void bucket_scan_k(const int* __restrict__ bucketCount,
                                                    int* __restrict__ bucketPtr,
                                                    int* __restrict__ bucketCursor,
                                                    int* __restrict__ rowPtr,
                                                    int B, int N, int E) {
    int lane = threadIdx.x;
    const int PT = (BMAX + 63) / 64;
    int v[PT]; int s = 0;
    #pragma unroll
    for (int t = 0; t < PT; t++) {
        int i = lane * PT + t;
        v[t] = (i < B) ? bucketCount[i] : 0;
        s += v[t];
    }
    int x = s;
    #pragma unroll
    for (int off = 1; off < 64; off <<= 1) {
        int y = __shfl_up(x, off, 64);
        if (lane >= off) x += y;
    }
    int run = x - s;
    #pragma unroll
    for (int t = 0; t < PT; t++) {
        int i = lane * PT + t;
        if (i < B) { bucketPtr[i] = run; bucketCursor[i] = run; }
        run += v[t];
    }
    if (lane == 63) bucketPtr[B] = x;
    if (lane == 0) rowPtr[N] = E;
}

__global__ __launch_bounds__(256) void bucket_scatter_k(const int* __restrict__ src,
                                                        const int* __restrict__ dst,
                                                        int* __restrict__ bucketCursor,
                                                        int* __restrict__ ebuf,
                                                        int E, int B) {
    __shared__ int cnt[BMAX];
    __shared__ int base[BMAX];
    __shared__ int cur[BMAX];
    for (int i = threadIdx.x; i < B; i += 256) { cnt[i] = 0; cur[i] = 0; }
    __syncthreads();
    int cbase = blockIdx.x * CHUNK;
    int d[EPT];
    #pragma unroll
    for (int t = 0; t < EPT; t++) {
        int e = cbase + t * 256 + threadIdx.x;
        d[t] = (e < E) ? dst[e] : -1;
        if (d[t] >= 0) atomicAdd(&cnt[d[t] >> BSHIFT], 1);
    }
    __syncthreads();
    for (int i = threadIdx.x; i < B; i += 256)
        if (cnt[i] > 0) base[i] = atomicAdd(&bucketCursor[i], cnt[i]);
    __syncthreads();
    #pragma unroll
    for (int t = 0; t < EPT; t++) {
        int e = cbase + t * 256 + threadIdx.x;
        if (d[t] >= 0) {
            int b = d[t] >> BSHIFT;
            int c = atomicAdd(&cur[b], 1);
            int pack = (src[e] & 0xFFFF) | ((d[t] & (BNODES - 1)) << 16);
            ebuf[base[b] + c] = pack;
        }
    }
}

__global__ __launch_bounds__(256) void csr_build_k(const int* __restrict__ ebuf,
                                                   const int* __restrict__ bucketPtr,
                                                   int* __restrict__ rowPtr,
                                                   float* __restrict__ dinv,
                                                   int* __restrict__ srcSorted,
                                                   int N) {
    __shared__ int deg[BNODES];
    __shared__ int rp[BNODES + 1];
    __shared__ int cur[BNODES];
    __shared__ int stage[CAP];
    int b = blockIdx.x;
    int nodeBase = b << BSHIFT;
    int nNodes = min(BNODES, N - nodeBase);
    int eBase = bucketPtr[b];
    int eCnt = bucketPtr[b + 1] - eBase;
    for (int i = threadIdx.x; i < BNODES; i += 256) deg[i] = 0;
    __syncthreads();
    for (int i = threadIdx.x; i < eCnt; i += 256)
        atomicAdd(&deg[(ebuf[eBase + i] >> 16) & (BNODES - 1)], 1);
    __syncthreads();
    if (threadIdx.x < 64) {
        int lane = threadIdx.x;
        int d0 = deg[2 * lane], d1 = deg[2 * lane + 1];
        int s = d0 + d1;
        int x = s;
        #pragma unroll
        for (int off = 1; off < 64; off <<= 1) {
            int y = __shfl_up(x, off, 64);
            if (lane >= off) x += y;
        }
        int ex = x - s;
        rp[2 * lane] = ex;
        rp[2 * lane + 1] = ex + d0;
        cur[2 * lane] = ex;
        cur[2 * lane + 1] = ex + d0;
        if (lane == 63) rp[BNODES] = x;
    }
    __syncthreads();
    for (int j = threadIdx.x; j < nNodes; j += 256) {
        rowPtr[nodeBase + j] = eBase + rp[j];
        int dg = deg[j];
        dinv[nodeBase + j] = rsqrtf((float)(dg > 1 ? dg : 1));
    }
    if (eCnt <= CAP) {
        for (int i = threadIdx.x; i < eCnt; i += 256) {
            int p = ebuf[eBase + i];
            int ld = (p >> 16) & (BNODES - 1);
            int pos = atomicAdd(&cur[ld], 1);
            stage[pos] = p & 0xFFFF;
        }
        __syncthreads();
        for (int i = threadIdx.x; i < eCnt; i += 256)
            srcSorted[eBase + i] = stage[i];
    } else {
        for (int i = threadIdx.x; i < eCnt; i += 256) {
            int p = ebuf[eBase + i];
            int ld = (p >> 16) & (BNODES - 1);
            int pos = atomicAdd(&cur[ld], 1);
            srcSorted[eBase + pos] = p & 0xFFFF;
        }
    }
}

// ----------------------------- dense1 --------------------------------------

#define D1_BLK 128
#define D1_PAD 68

__global__ __launch_bounds__(D1_BLK) void dense1_k(const float* __restrict__ Xg,
                                                   const float* __restrict__ W1,
                                                   const float* __restrict__ b1,
                                                   float* __restrict__ h1, int N) {
    __shared__ float lds[D1_BLK * D1_PAD];
    int n0 = blockIdx.x * D1_BLK;
    int n = n0 + threadIdx.x;
    bool act = (n < N);
    const float4* W = (const float4*)W1;
    const float4* B = (const float4*)b1;
    float4 acc[16];
    #pragma unroll
    for (int j = 0; j < 16; j++) acc[j] = B[j];
    if (act) {
        const float4* X = (const float4*)Xg + (size_t)n * 32;
        float4 a = X[0];
        #pragma unroll 1
        for (int kc = 0; kc < 32; kc++) {
            float4 an = a;
            if (kc + 1 < 32) an = X[kc + 1];
            const float4* wrow = W + kc * 64;
            #pragma unroll
            for (int j = 0; j < 16; j++) {
                fma4(acc[j], a.x, wrow[j]);
                fma4(acc[j], a.y, wrow[16 + j]);
                fma4(acc[j], a.z, wrow[32 + j]);
                fma4(acc[j], a.w, wrow[48 + j]);
            }
            a = an;
        }
    }
    float* myrow = &lds[threadIdx.x * D1_PAD];
    #pragma unroll
    for (int j = 0; j < 16; j++) {
        float4 v = acc[j];
        *(float4*)&myrow[4 * j] = make_float4(fmaxf(v.x, 0.f), fmaxf(v.y, 0.f),
                                              fmaxf(v.z, 0.f), fmaxf(v.w, 0.f));
    }
    __syncthreads();
    float4* o4 = (float4*)h1;
    #pragma unroll
    for (int r = 0; r < 16; r++) {
        int idx = r * D1_BLK + threadIdx.x;
        int row = idx >> 4, col = idx & 15;
        int gn = n0 + row;
        if (gn < N) o4[(size_t)gn * 16 + col] = *(float4*)&lds[row * D1_PAD + col * 4];
    }
}

// ------------------- shared GEMV / coop-write building blocks ---------------

#define D2_BLK 128
#define D2_PAD 68

// Stage acc2 rows into LDS and cooperatively write fp32 AoS rows (coalesced).
#define COOP_WRITE_F32(OUT) do {                                               \
    __syncthreads();                                                           \
    float* myrow_ = &lds[threadIdx.x * D2_PAD];                                \
    _Pragma("unroll")                                                          \
    for (int j_ = 0; j_ < 16; j_++) *(float4*)&myrow_[4 * j_] = acc2[j_];      \
    __syncthreads();                                                           \
    float4* o4_ = (float4*)(OUT);                                              \
    _Pragma("unroll")                                                          \
    for (int r_ = 0; r_ < 16; r_++) {                                          \
        int idx_ = r_ * D2_BLK + threadIdx.x;                                  \
        int row_ = idx_ >> 4, col_ = idx_ & 15;                                \
        int gn_ = n0 + row_;                                                   \
        if (gn_ < N)                                                           \
            o4_[(size_t)gn_ * 16 + col_] =                                     \
                *(float4*)&lds[row_ * D2_PAD + col_ * 4];                      \
    }                                                                          \
} while (0)

// acc2 += (SX * src_row) @ W  (64x64 weight block at WB4, float4 view)
#define GEMV16(SRC4, WB4, SX) do {                                             \
    _Pragma("unroll 1")                                                        \
    for (int kc_ = 0; kc_ < 16; kc_++) {                                       \
        float4 a_ = (SRC4)[kc_];                                               \
        a_.x *= (SX); a_.y *= (SX); a_.z *= (SX); a_.w *= (SX);                \
        const float4* wr_ = (WB4) + kc_ * 64;                                  \
        _Pragma("unroll")                                                      \
        for (int j_ = 0; j_ < 16; j_++) {                                      \
            fma4(acc2[j_], a_.x, wr_[j_]);                                     \
            fma4(acc2[j_], a_.y, wr_[16 + j_]);                                \
            fma4(acc2[j_], a_.z, wr_[32 + j_]);                                \
            fma4(acc2[j_], a_.w, wr_[48 + j_]);                                \
        }                                                                      \
    }                                                                          \
} while (0)

// ----------------------------- dense2res -----------------------------------
// Thread/node. h = relu(h1@W2+b2); outputs: hg, hs=f16(h*dinv), th, res,
// P_h = h@Wf1top, QhB = h@Wf1bot+bf1, R_h = h@W3, R_resb = 0.8*res@W3 + b3.

__global__ __launch_bounds__(D2_BLK) void dense2res_k(const float* __restrict__ h1,
                                                      const float* __restrict__ W2,
                                                      const float* __restrict__ b2,
                                                      const float* __restrict__ Wres,
                                                      const float* __restrict__ bres,
                                                      const float* __restrict__ Wattn,
                                                      const float* __restrict__ Wf1,
                                                      const float* __restrict__ bf1,
                                                      const float* __restrict__ W3,
                                                      const float* __restrict__ b3,
                                                      const float* __restrict__ dinv,
                                                      float* __restrict__ hg,
                                                      float2* __restrict__ hs2,
                                                      float* __restrict__ resg,
                                                      float* __restrict__ Ph,
                                                      float* __restrict__ QhB,
                                                      float* __restrict__ Rh,
                                                      float* __restrict__ Rresb,
                                                      float* __restrict__ thv, int N) {
    __shared__ float lds[D2_BLK * D2_PAD];
    int n0 = blockIdx.x * D2_BLK;
    int n = n0 + threadIdx.x;
    bool act = (n < N);
    int nn = act ? n : n0;            // safe row index for streaming reads
    const float4* W = (const float4*)W2;
    const float4* B = (const float4*)b2;
    float4 acc[16];
    #pragma unroll
    for (int j = 0; j < 16; j++) acc[j] = B[j];
    if (act) {
        const float4* X = (const float4*)h1 + (size_t)n * 16;
        float4 a = X[0];
        #pragma unroll 1
        for (int kc = 0; kc < 16; kc++) {
            float4 an = a;
            if (kc + 1 < 16) an = X[kc + 1];
            const float4* wrow = W + kc * 64;
            #pragma unroll
            for (int j = 0; j < 16; j++) {
                fma4(acc[j], a.x, wrow[j]);
                fma4(acc[j], a.y, wrow[16 + j]);
                fma4(acc[j], a.z, wrow[32 + j]);
                fma4(acc[j], a.w, wrow[48 + j]);
            }
            a = an;
        }
    }
    // relu; stage h; attention score
    const float4* Wa = (const float4*)Wattn;
    float th = 0.f;
    float* myrow = &lds[threadIdx.x * D2_PAD];
    #pragma unroll
    for (int j = 0; j < 16; j++) {
        float4 v = acc[j];
        v.x = fmaxf(v.x, 0.f); v.y = fmaxf(v.y, 0.f);
        v.z = fmaxf(v.z, 0.f); v.w = fmaxf(v.w, 0.f);
        *(float4*)&myrow[4 * j] = v;
        float4 w = Wa[j];
        th += v.x * w.x + v.y * w.y + v.z * w.z + v.w * w.w;
    }
    if (act) thv[n] = th;
    __syncthreads();
    // coop contiguous writes of h (fp32) and hs (f16 packed)
    float4* h4 = (float4*)hg;
    #pragma unroll
    for (int r = 0; r < 16; r++) {
        int idx = r * D2_BLK + threadIdx.x;
        int row = idx >> 4, col = idx & 15;
        int gn = n0 + row;
        if (gn < N) {
            float4 v = *(float4*)&lds[row * D2_PAD + col * 4];
            h4[(size_t)gn * 16 + col] = v;
            float di = dinv[gn];
            hs2[(size_t)gn * 16 + col] =
                pack_half4(v.x * di, v.y * di, v.z * di, v.w * di);
        }
    }
    __syncthreads();   // hg fully written & visible block-wide
    const float4* hr = (const float4*)hg + (size_t)nn * 16;
    float4 acc2[16];
    const float4* Wf14 = (const float4*)Wf1;
    const float4* W34 = (const float4*)W3;
    // ---- res = h @ Wres + bres ----
    {
        const float4* BB = (const float4*)bres;
        #pragma unroll
        for (int j = 0; j < 16; j++) acc2[j] = BB[j];
        GEMV16(hr, (const float4*)Wres, 1.0f);
        COOP_WRITE_F32(resg);
    }
    // ---- P_h = h @ Wf1[0:64] ----
    {
        #pragma unroll
        for (int j = 0; j < 16; j++) acc2[j] = make_float4(0.f, 0.f, 0.f, 0.f);
        GEMV16(hr, Wf14, 1.0f);
        COOP_WRITE_F32(Ph);
    }
    // ---- QhB = h @ Wf1[64:128] + bf1 ----
    {
        const float4* BB = (const float4*)bf1;
        #pragma unroll
        for (int j = 0; j < 16; j++) acc2[j] = BB[j];
        GEMV16(hr, Wf14 + 1024, 1.0f);
        COOP_WRITE_F32(QhB);
    }
    // ---- R_h = h @ W3 ----
    {
        #pragma unroll
        for (int j = 0; j < 16; j++) acc2[j] = make_float4(0.f, 0.f, 0.f, 0.f);
        GEMV16(hr, W34, 1.0f);
        COOP_WRITE_F32(Rh);
    }
    // ---- R_resb = 0.8 * res @ W3 + b3  (resg visible: barriers above) ----
    {
        const float4* rr = (const float4*)resg + (size_t)nn * 16;
        const float4* BB = (const float4*)b3;
        #pragma unroll
        for (int j = 0; j < 16; j++) acc2[j] = BB[j];
        GEMV16(rr, W34, 0.8f);
        COOP_WRITE_F32(Rresb);
    }
}

// ----------------------------- dense_u1 ------------------------------------
// Thread/node: P_u1 = u1@Wf1top, R_u1 = u1@W3.

__global__ __launch_bounds__(D2_BLK) void dense_u1_k(const float* __restrict__ u1,
                                                     const float* __restrict__ Wf1,
                                                     const float* __restrict__ W3,
                                                     float* __restrict__ Pu1,
                                                     float* __restrict__ Ru1, int N) {
    __shared__ float lds[D2_BLK * D2_PAD];
    int n0 = blockIdx.x * D2_BLK;
    int n = n0 + threadIdx.x;
    int nn = (n < N) ? n : n0;
    const float4* ur = (const float4*)u1 + (size_t)nn * 16;
    float4 acc2[16];
    {
        #pragma unroll
        for (int j = 0; j < 16; j++) acc2[j] = make_float4(0.f, 0.f, 0.f, 0.f);
        GEMV16(ur, (const float4*)Wf1, 1.0f);
        COOP_WRITE_F32(Pu1);
    }
    {
        #pragma unroll
        for (int j = 0; j < 16; j++) acc2[j] = make_float4(0.f, 0.f, 0.f, 0.f);
        GEMV16(ur, (const float4*)W3, 1.0f);
        COOP_WRITE_F32(Ru1);
    }
}

// ----------------------------- SPMM (spmm1) --------------------------------
// Wave per node (4/block). 16 lanes per f16 row (float2 loads), 4 chains,
// fp32 accum. Outputs u1 (fp32 AoS), u1s (f16), ta = u1.Wattn.

__global__ __launch_bounds__(256) void spmm_k(const float2* __restrict__ xs,
                                              const int* __restrict__ srcs,
                                              const int* __restrict__ rowPtr,
                                              const float* __restrict__ dinv,
                                              const float* __restrict__ Wattn,
                                              float4* __restrict__ u,
                                              float2* __restrict__ us,
                                              float* __restrict__ tav, int N) {
    int node = (blockIdx.x * 256 + threadIdx.x) >> 6;
    if (node >= N) return;
    int lane = threadIdx.x & 63;
    int sub = lane >> 4;
    int q = lane & 15;
    int s0 = rowPtr[node], s1 = rowPtr[node + 1];
    float4 a0 = make_float4(0.f, 0.f, 0.f, 0.f);
    float4 a1 = a0, a2 = a0, a3 = a0;
    int i = s0 + sub;
    for (; i + 12 < s1; i += 16) {
        int sA = srcs[i];
        int sB = srcs[i + 4];
        int sC = srcs[i + 8];
        int sD = srcs[i + 12];
        float2 vA = xs[(size_t)sA * 16 + q];
        float2 vB = xs[(size_t)sB * 16 + q];
        float2 vC = xs[(size_t)sC * 16 + q];
        float2 vD = xs[(size_t)sD * 16 + q];
        acch4(a0, vA); acch4(a1, vB); acch4(a2, vC); acch4(a3, vD);
    }
    for (; i + 4 < s1; i += 8) {
        int sA = srcs[i];
        int sB = srcs[i + 4];
        float2 vA = xs[(size_t)sA * 16 + q];
        float2 vB = xs[(size_t)sB * 16 + q];
        acch4(a0, vA); acch4(a1, vB);
    }
    if (i < s1) {
        float2 vA = xs[(size_t)srcs[i] * 16 + q];
        acch4(a0, vA);
    }
    a0.x += a1.x + a2.x + a3.x;
    a0.y += a1.y + a2.y + a3.y;
    a0.z += a1.z + a2.z + a3.z;
    a0.w += a1.w + a2.w + a3.w;
    #pragma unroll
    for (int m = 16; m < 64; m <<= 1) {
        a0.x += __shfl_xor(a0.x, m, 64);
        a0.y += __shfl_xor(a0.y, m, 64);
        a0.z += __shfl_xor(a0.z, m, 64);
        a0.w += __shfl_xor(a0.w, m, 64);
    }
    if (sub == 0) {
        float di = dinv[node];
        float4 r = make_float4(a0.x * di, a0.y * di, a0.z * di, a0.w * di);
        u[(size_t)node * 16 + q] = r;
        us[(size_t)node * 16 + q] =
            pack_half4(r.x * di, r.y * di, r.z * di, r.w * di);
        float4 w = ((const float4*)Wattn)[q];
        float p = r.x * w.x + r.y * w.y + r.z * w.z + r.w * w.w;
        #pragma unroll
        for (int m = 1; m < 16; m <<= 1) p += __shfl_xor(p, m, 64);
        if (lane == 0) tav[node] = p;
    }
}

// ----------------------------- spmm2 (pure gather) --------------------------
// Wave per node (4/block). u2 = dinv * (A^T u1s); writes u2s (f16 row) and
// tb = u2 . Wattn. No dense work here -> exposes the gather floor.

__global__ __launch_bounds__(256) void spmm2_k(const float2* __restrict__ u1s,
                                               const int* __restrict__ srcs,
                                               const int* __restrict__ rowPtr,
                                               const float* __restrict__ dinv,
                                               const float* __restrict__ Wattn,
                                               float2* __restrict__ u2s,
                                               float* __restrict__ tbv, int N) {
    int node = (blockIdx.x * 256 + threadIdx.x) >> 6;
    if (node >= N) return;
    int lane = threadIdx.x & 63;
    int sub = lane >> 4;
    int q = lane & 15;
    int s0 = rowPtr[node], s1 = rowPtr[node + 1];
    float4 a0 = make_float4(0.f, 0.f, 0.f, 0.f);
    float4 a1 = a0, a2 = a0, a3 = a0;
    int i = s0 + sub;
    for (; i + 12 < s1; i += 16) {
        int sA = srcs[i];
        int sB = srcs[i + 4];
        int sC = srcs[i + 8];
        int sD = srcs[i + 12];
        float2 vA = u1s[(size_t)sA * 16 + q];
        float2 vB = u1s[(size_t)sB * 16 + q];
        float2 vC = u1s[(size_t)sC * 16 + q];
        float2 vD = u1s[(size_t)sD * 16 + q];
        acch4(a0, vA); acch4(a1, vB); acch4(a2, vC); acch4(a3, vD);
    }
    for (; i + 4 < s1; i += 8) {
        int sA = srcs[i];
        int sB = srcs[i + 4];
        float2 vA = u1s[(size_t)sA * 16 + q];
        float2 vB = u1s[(size_t)sB * 16 + q];
        acch4(a0, vA); acch4(a1, vB);
    }
    if (i < s1) {
        float2 vA = u1s[(size_t)srcs[i] * 16 + q];
        acch4(a0, vA);
    }
    a0.x += a1.x + a2.x + a3.x;
    a0.y += a1.y + a2.y + a3.y;
    a0.z += a1.z + a2.z + a3.z;
    a0.w += a1.w + a2.w + a3.w;
    #pragma unroll
    for (int m = 16; m < 64; m <<= 1) {
        a0.x += __shfl_xor(a0.x, m, 64);
        a0.y += __shfl_xor(a0.y, m, 64);
        a0.z += __shfl_xor(a0.z, m, 64);
        a0.w += __shfl_xor(a0.w, m, 64);
    }
    if (sub == 0) {
        float di = dinv[node];
        float4 r = make_float4(a0.x * di, a0.y * di, a0.z * di, a0.w * di);
        u2s[(size_t)node * 16 + q] = pack_half4(r.x, r.y, r.z, r.w);
        float4 w = ((const float4*)Wattn)[q];
        float p = r.x * w.x + r.y * w.y + r.z * w.z + r.w * w.w;
        #pragma unroll
        for (int m = 1; m < 16; m <<= 1) p += __shfl_xor(p, m, 64);
        if (lane == 0) tbv[node] = p;
    }
}

// ----------------------------- final ----------------------------------------
// Thread/node: softmax -> ca,cb,cc; P_u2 = u2@Wf1top; t/fw; R_u2 = u2@W3;
// g; logits. All weight loads thread-uniform (scalar); no runtime reg idx.

__global__ __launch_bounds__(256) void final_k(const float4* __restrict__ u2s4,
                                               const float* __restrict__ thv,
                                               const float* __restrict__ tav,
                                               const float* __restrict__ tbv,
                                               const float* __restrict__ battn,
                                               const float* __restrict__ Ph,
                                               const float* __restrict__ Pu1,
                                               const float* __restrict__ QhB,
                                               const float* __restrict__ Rh,
                                               const float* __restrict__ Ru1,
                                               const float* __restrict__ Rresb,
                                               const float* __restrict__ Wf1,
                                               const float* __restrict__ W3,
                                               const float* __restrict__ Wf2,
                                               const float* __restrict__ bf2,
                                               const float* __restrict__ W4,
                                               const float* __restrict__ b4,
                                               float2* __restrict__ out, int N) {
    int n = blockIdx.x * 256 + threadIdx.x;
    if (n >= N) return;
    float th = thv[n], ta = tav[n], tb = tbv[n], ba = battn[0];
    float s0 = 0.75f * th + 1.5f * ta + 0.75f * tb + ba;
    float s1 = 1.5f * th - 1.5f * tb + ba;
    float s2 = 0.75f * th - 1.5f * ta + 0.75f * tb + ba;
    float mx = fmaxf(s0, fmaxf(s1, s2));
    float e0 = expf(s0 - mx), e1 = expf(s1 - mx), e2 = expf(s2 - mx);
    float inv = 1.f / (e0 + e1 + e2);
    float w0 = e0 * inv, w1 = e1 * inv, w2 = e2 * inv;
    float ca = 0.75f * w0 + 1.5f * w1 + 0.75f * w2;
    float cb = 1.5f * (w0 - w2);
    float cc = 0.75f * w0 - 1.5f * w1 + 0.75f * w2;

    const float4* u2r = u2s4 + (size_t)n * 8;   // 8 float4 = 64 halves
    float4 acc[16];

    // ---- P_u2 = u2 @ Wf1[0:64] ----
    {
        const float4* WT = (const float4*)Wf1;
        #pragma unroll
        for (int j = 0; j < 16; j++) acc[j] = make_float4(0.f, 0.f, 0.f, 0.f);
        #pragma unroll 1
        for (int t = 0; t < 8; t++) {
            union { float4 f; __half2 h[4]; } u; u.f = u2r[t];
            float a[8];
            #pragma unroll
            for (int e = 0; e < 4; e++) {
                float2 v = __half22float2(u.h[e]);
                a[2 * e] = v.x; a[2 * e + 1] = v.y;
            }
            const float4* wr = WT + (t * 8) * 16;
            #pragma unroll
            for (int e = 0; e < 8; e++) {
                #pragma unroll
                for (int j = 0; j < 16; j++) fma4(acc[j], a[e], wr[e * 16 + j]);
            }
        }
    }
    // ---- t = relu(ca*Ph + cb*Pu1 + cc*Pu2 + QhB); fw = sigmoid(t.Wf2+bf2) --
    const float4* Ph4 = (const float4*)Ph + (size_t)n * 16;
    const float4* Pu14 = (const float4*)Pu1 + (size_t)n * 16;
    const float4* Qh4 = (const float4*)QhB + (size_t)n * 16;
    const float4* Wf24 = (const float4*)Wf2;
    float fwacc = 0.f;
    #pragma unroll
    for (int j = 0; j < 16; j++) {
        float4 ph = Ph4[j], pu = Pu14[j], qh = Qh4[j], pw = acc[j];
        float4 tt;
        tt.x = fmaxf(ca * ph.x + cb * pu.x + cc * pw.x + qh.x, 0.f);
        tt.y = fmaxf(ca * ph.y + cb * pu.y + cc * pw.y + qh.y, 0.f);
        tt.z = fmaxf(ca * ph.z + cb * pu.z + cc * pw.z + qh.z, 0.f);
        tt.w = fmaxf(ca * ph.w + cb * pu.w + cc * pw.w + qh.w, 0.f);
        float4 wf = Wf24[j];
        fwacc += tt.x * wf.x + tt.y * wf.y + tt.z * wf.z + tt.w * wf.w;
    }
    float fw = 1.f / (1.f + expf(-(fwacc + bf2[0])));

    // ---- R_u2 = u2 @ W3 ----
    {
        const float4* WT = (const float4*)W3;
        #pragma unroll
        for (int j = 0; j < 16; j++) acc[j] = make_float4(0.f, 0.f, 0.f, 0.f);
        #pragma unroll 1
        for (int t = 0; t < 8; t++) {
            union { float4 f; __half2 h[4]; } u; u.f = u2r[t];
            float a[8];
            #pragma unroll
            for (int e = 0; e < 4; e++) {
                float2 v = __half22float2(u.h[e]);
                a[2 * e] = v.x; a[2 * e + 1] = v.y;
            }
            const float4* wr = WT + (t * 8) * 16;
            #pragma unroll
            for (int e = 0; e < 8; e++) {
                #pragma unroll
                for (int j = 0; j < 16; j++) fma4(acc[j], a[e], wr[e * 16 + j]);
            }
        }
    }
    // ---- g = relu(0.1fw*(ca*Rh+cb*Ru1+cc*Ru2) + (1-fw)*Rh + Rresb); logits -
    const float4* Rh4 = (const float4*)Rh + (size_t)n * 16;
    const float4* Ru14 = (const float4*)Ru1 + (size_t)n * 16;
    const float4* Rb4 = (const float4*)Rresb + (size_t)n * 16;
    const float4* W44 = (const float4*)W4;
    float sa = 0.1f * fw;
    float sh = 1.f - fw;
    float l0 = 0.f, l1 = 0.f;
    #pragma unroll
    for (int j = 0; j < 16; j++) {
        float4 rh = Rh4[j], ru = Ru14[j], rb = Rb4[j], rw = acc[j];
        float4 g;
        g.x = fmaxf(sa * (ca * rh.x + cb * ru.x + cc * rw.x) + sh * rh.x + rb.x, 0.f);
        g.y = fmaxf(sa * (ca * rh.y + cb * ru.y + cc * rw.y) + sh * rh.y + rb.y, 0.f);
        g.z = fmaxf(sa * (ca * rh.z + cb * ru.z + cc * rw.z) + sh * rh.z + rb.z, 0.f);
        g.w = fmaxf(sa * (ca * rh.w + cb * ru.w + cc * rw.w) + sh * rh.w + rb.w, 0.f);
        float4 wa = W44[j * 2], wb = W44[j * 2 + 1];
        l0 += g.x * wa.x + g.y * wa.z + g.z * wb.x + g.w * wb.z;
        l1 += g.x * wa.y + g.y * wa.w + g.z * wb.y + g.w * wb.w;
    }
    out[n] = make_float2(l0 + b4[0], l1 + b4[1]);
}

// ----------------------------- launch --------------------------------------

extern "C" void kernel_launch(void* const* d_in, const int* in_sizes, int n_in,
                              void* d_out, int out_size, void* d_ws, size_t ws_size,
                              hipStream_t stream) {
    const float* in_feat = (const float*)d_in[0];
    const int*   src     = (const int*)d_in[1];
    const int*   dst     = (const int*)d_in[2];
    const float* W1   = (const float*)d_in[3];
    const float* b1   = (const float*)d_in[4];
    const float* W2   = (const float*)d_in[5];
    const float* b2   = (const float*)d_in[6];
    const float* Wres = (const float*)d_in[7];
    const float* bres = (const float*)d_in[8];
    const float* Wattn = (const float*)d_in[9];
    const float* battn = (const float*)d_in[10];
    const float* Wf1  = (const float*)d_in[11];
    const float* bf1  = (const float*)d_in[12];
    const float* Wf2  = (const float*)d_in[13];
    const float* bf2  = (const float*)d_in[14];
    const float* W3   = (const float*)d_in[15];
    const float* b3   = (const float*)d_in[16];
    const float* W4   = (const float*)d_in[17];
    const float* b4   = (const float*)d_in[18];

    const int N = in_sizes[0] / 128;
    const int E = in_sizes[1];
    const int B = (N + BNODES - 1) >> BSHIFT;

    char* p = (char*)d_ws;
    auto take = [&](size_t bytes) -> char* {
        char* r = p;
        p += (bytes + 255) & ~(size_t)255;
        return r;
    };
    int*   bucketCount  = (int*)take((size_t)(B + 1) * 4);
    int*   bucketPtr    = (int*)take((size_t)(B + 1) * 4);
    int*   bucketCursor = (int*)take((size_t)(B + 1) * 4);
    int*   rowPtr       = (int*)take((size_t)(N + 1) * 4);
    float* dinv         = (float*)take((size_t)N * 4);
    int*   srcSorted    = (int*)take((size_t)E * 4);
    float* thv          = (float*)take((size_t)N * 4);
    float* tav          = (float*)take((size_t)N * 4);
    float* tbv          = (float*)take((size_t)N * 4);
    float* h1   = (float*)take((size_t)N * 256);   // also: ebuf, then Ph
    float* h    = (float*)take((size_t)N * 256);   // later reused as Ru1
    float* hs   = (float*)take((size_t)N * 128);   // f16 packed
    float* res  = (float*)take((size_t)N * 256);   // later reused as Pu1
    float* u1   = (float*)take((size_t)N * 256);
    float* u1s  = (float*)take((size_t)N * 128);   // f16 packed
    float* u2s  = (float*)take((size_t)N * 128);   // f16 packed
    float* QhB  = (float*)take((size_t)N * 256);
    float* Rh   = (float*)take((size_t)N * 256);
    float* Rresb= (float*)take((size_t)N * 256);
    int*   ebuf = (int*)h1;    // dead before dense1 writes h1 (stream order)
    float* Ph   = h1;          // h1 dead after dense2res phase-1 reads own row
    float* Pu1  = res;         // res dead after dense2res (R_resb consumed it)
    float* Ru1  = h;           // h raw dead after dense2res

    int eb = (E + CHUNK - 1) / CHUNK;
    int d1b = (N + D1_BLK - 1) / D1_BLK;
    int d2b = (N + D2_BLK - 1) / D2_BLK;
    int spb = (N * 64 + 255) / 256;
    int fnb = (N + 255) / 256;

    hipMemsetAsync(bucketCount, 0, (size_t)B * 4, stream);
    bucket_count_k<<<eb, 256, 0, stream>>>(dst, bucketCount, E, B);
    bucket_scan_k<<<1, 64, 0, stream>>>(bucketCount, bucketPtr, bucketCursor,
                                        rowPtr, B, N, E);
    bucket_scatter_k<<<eb, 256, 0, stream>>>(src, dst, bucketCursor, ebuf, E, B);
    csr_build_k<<<B, 256, 0, stream>>>(ebuf, bucketPtr, rowPtr, dinv, srcSorted, N);

    dense1_k<<<d1b, D1_BLK, 0, stream>>>(in_feat, W1, b1, h1, N);
    dense2res_k<<<d2b, D2_BLK, 0, stream>>>(h1, W2, b2, Wres, bres, Wattn,
                                            Wf1, bf1, W3, b3, dinv,
                                            h, (float2*)hs, res,
                                            Ph, QhB, Rh, Rresb, thv, N);

    spmm_k<<<spb, 256, 0, stream>>>((const float2*)hs, srcSorted, rowPtr, dinv,
                                    Wattn, (float4*)u1, (float2*)u1s, tav, N);

    dense_u1_k<<<d2b, D2_BLK, 0, stream>>>(u1, Wf1, W3, Pu1, Ru1, N);

    spmm2_k<<<spb, 256, 0, stream>>>((const float2*)u1s, srcSorted, rowPtr, dinv,
                                     Wattn, (float2*)u2s, tbv, N);

    final_k<<<fnb, 256, 0, stream>>>((const float4*)u2s, thv, tav, tbv, battn,
                                     Ph, Pu1, QhB, Rh, Ru1, Rresb,
                                     Wf1, W3, Wf2, bf2, W4, b4,
                                     (float2*)d_out, N);
}